// Round 1
// baseline (2459.568 us; speedup 1.0000x reference)
//
#include <hip/hip_runtime.h>

#define NN 50000
#define NE 800000
#define NL 12
#define DD 64

// ---------------------------------------------------------------------------
// Detect whether edge_index is stored as int64 (odd 32-bit words all zero)
// or int32. Writes flag=1 for int64, 0 for int32.
// ---------------------------------------------------------------------------
__global__ __launch_bounds__(256) void detect_i64(const unsigned int* __restrict__ w,
                                                  int* __restrict__ flag) {
    __shared__ unsigned int red[256];
    unsigned int v = 0;
    for (int i = threadIdx.x; i < 4096; i += 256) v |= w[2 * i + 1];
    red[threadIdx.x] = v;
    __syncthreads();
    for (int s = 128; s > 0; s >>= 1) {
        if (threadIdx.x < s) red[threadIdx.x] |= red[threadIdx.x + s];
        __syncthreads();
    }
    if (threadIdx.x == 0) *flag = (red[0] == 0u) ? 1 : 0;
}

// ---------------------------------------------------------------------------
// Histogram of destination counts.
// ---------------------------------------------------------------------------
__global__ __launch_bounds__(256) void hist_k(const void* __restrict__ eidx,
                                              const int* __restrict__ flag,
                                              int* __restrict__ cnt) {
    int e = blockIdx.x * 256 + threadIdx.x;
    if (e >= NE) return;
    int dst;
    if (*flag) dst = (int)((const long long*)eidx)[NE + e];
    else       dst = ((const int*)eidx)[NE + e];
    atomicAdd(&cnt[dst], 1);
}

// ---------------------------------------------------------------------------
// Single-block exclusive scan over cnt[NN] -> offs[NN+1], also copies to cursor.
// 1024 threads, wave-level shfl scan + cross-wave LDS scan (2 syncs/tile).
// ---------------------------------------------------------------------------
__global__ __launch_bounds__(1024) void scan_k(const int* __restrict__ cnt,
                                               int* __restrict__ offs,
                                               int* __restrict__ cursor) {
    __shared__ int wsum[16];
    __shared__ int carry_s;
    int tid = threadIdx.x;
    int lane = tid & 63;
    int wv = tid >> 6;
    if (tid == 0) carry_s = 0;
    __syncthreads();
    for (int base = 0; base < NN; base += 1024) {
        int i = base + tid;
        int v = (i < NN) ? cnt[i] : 0;
        int incl = v;
        #pragma unroll
        for (int d = 1; d < 64; d <<= 1) {
            int t = __shfl_up(incl, d);
            if (lane >= d) incl += t;
        }
        if (lane == 63) wsum[wv] = incl;
        __syncthreads();
        if (wv == 0) {
            int s = (lane < 16) ? wsum[lane] : 0;
            #pragma unroll
            for (int d = 1; d < 16; d <<= 1) {
                int t = __shfl_up(s, d);
                if (lane >= d) s += t;
            }
            if (lane < 16) wsum[lane] = s;  // inclusive over waves
        }
        __syncthreads();
        int wbase = (wv == 0) ? 0 : wsum[wv - 1];
        int carry = carry_s;
        int excl = carry + wbase + incl - v;
        if (i < NN) { offs[i] = excl; cursor[i] = excl; }
        __syncthreads();
        if (tid == 1023) carry_s = carry + wsum[15];
        __syncthreads();
    }
    if (threadIdx.x == 0) offs[NN] = carry_s;
}

// ---------------------------------------------------------------------------
// Scatter edges into CSR slots: csr[pos] = {src, weight_bits}.
// ---------------------------------------------------------------------------
__global__ __launch_bounds__(256) void fill_k(const void* __restrict__ eidx,
                                              const float* __restrict__ ew,
                                              const int* __restrict__ flag,
                                              int* __restrict__ cursor,
                                              int2* __restrict__ csr) {
    int e = blockIdx.x * 256 + threadIdx.x;
    if (e >= NE) return;
    int src, dst;
    if (*flag) {
        const long long* p = (const long long*)eidx;
        src = (int)p[e];
        dst = (int)p[NE + e];
    } else {
        const int* p = (const int*)eidx;
        src = p[e];
        dst = p[NE + e];
    }
    int pos = atomicAdd(&cursor[dst], 1);
    csr[pos] = make_int2(src, __float_as_int(ew[e]));
}

// ---------------------------------------------------------------------------
// One fused layer: per node (one wave, lane = channel):
//   aggr = sum_e w_e * xin[src_e]        (CSR loop, coalesced 256B row gathers)
//   an   = l2norm(aggr)
//   out  = b + an @ W[0:64] + xin[node] @ W[64:128]   (W staged in LDS)
//   xout[node] = l2norm(out)
// ---------------------------------------------------------------------------
__global__ __launch_bounds__(256) void layer_k(const float* __restrict__ xin,
                                               const float* __restrict__ Wl,
                                               const float* __restrict__ bl,
                                               const int* __restrict__ offs,
                                               const int2* __restrict__ csr,
                                               float* __restrict__ xout) {
    __shared__ float Ws[128 * 64];
    int tid = threadIdx.x;
    // stage W[i] (128x64 f32 = 32 KB) into LDS, vectorized
    const float4* Wv = (const float4*)Wl;
    float4* Wsv = (float4*)Ws;
    #pragma unroll
    for (int i = 0; i < 8; ++i) Wsv[tid + 256 * i] = Wv[tid + 256 * i];
    __syncthreads();

    int wave = tid >> 6;
    int lane = tid & 63;
    int node = blockIdx.x * 4 + wave;

    int e0 = offs[node];
    int e1 = offs[node + 1];
    float acc = 0.f;
    for (int e = e0; e < e1; ++e) {
        int2 sw = csr[e];
        float w = __int_as_float(sw.y);
        acc += w * xin[(size_t)sw.x * DD + lane];
    }
    // l2norm of aggr across the wave
    float sq = acc * acc;
    #pragma unroll
    for (int off = 32; off > 0; off >>= 1) sq += __shfl_xor(sq, off);
    float an = acc / fmaxf(sqrtf(sq), 1e-12f);

    float xl = xin[(size_t)node * DD + lane];
    float out = bl[lane];
    #pragma unroll
    for (int k = 0; k < 64; ++k) {
        float ak = __shfl(an, k);   // compile-time lane -> broadcast
        float xk = __shfl(xl, k);
        out += ak * Ws[k * 64 + lane] + xk * Ws[(64 + k) * 64 + lane];
    }
    float osq = out * out;
    #pragma unroll
    for (int off = 32; off > 0; off >>= 1) osq += __shfl_xor(osq, off);
    xout[(size_t)node * DD + lane] = out / fmaxf(sqrtf(osq), 1e-12f);
}

// ---------------------------------------------------------------------------
extern "C" void kernel_launch(void* const* d_in, const int* in_sizes, int n_in,
                              void* d_out, int out_size, void* d_ws, size_t ws_size,
                              hipStream_t stream) {
    const float* x0  = (const float*)d_in[0];
    const void*  eidx = d_in[1];
    const float* ew  = (const float*)d_in[2];
    const float* W   = (const float*)d_in[3];
    const float* b   = (const float*)d_in[4];
    float* out = (float*)d_out;

    char* p = (char*)d_ws;
    auto alloc = [&](size_t bytes) {
        char* r = p;
        p += (bytes + 255) & ~(size_t)255;
        return r;
    };
    int*   flag   = (int*)alloc(4);
    int*   cnt    = (int*)alloc((size_t)NN * 4);
    int*   offs   = (int*)alloc((size_t)(NN + 1) * 4);
    int*   cursor = (int*)alloc((size_t)NN * 4);
    int2*  csr    = (int2*)alloc((size_t)NE * 8);
    float* bufA   = (float*)alloc((size_t)NN * DD * 4);
    // total ws use: ~20 MB

    hipMemsetAsync(cnt, 0, (size_t)NN * 4, stream);
    detect_i64<<<1, 256, 0, stream>>>((const unsigned int*)eidx, flag);
    hist_k<<<(NE + 255) / 256, 256, 0, stream>>>(eidx, flag, cnt);
    scan_k<<<1, 1024, 0, stream>>>(cnt, offs, cursor);
    fill_k<<<(NE + 255) / 256, 256, 0, stream>>>(eidx, ew, flag, cursor, csr);

    for (int i = 0; i < NL; ++i) {
        const float* xin = (i == 0) ? x0 : ((i % 2 == 1) ? bufA : out);
        float* xout = (i % 2 == 0) ? bufA : out;
        layer_k<<<NN / 4, 256, 0, stream>>>(xin, W + (size_t)i * 128 * 64,
                                            b + (size_t)i * 64, offs, csr, xout);
    }
}

// Round 2
// 1805.181 us; speedup vs baseline: 1.3625x; 1.3625x over previous
//
#include <hip/hip_runtime.h>

#define NN 50000
#define NE 800000
#define NL 12
#define DD 64

// ---------------------------------------------------------------------------
// Detect whether edge_index is stored as int64 (odd 32-bit words all zero)
// or int32. Writes flag=1 for int64, 0 for int32.
// ---------------------------------------------------------------------------
__global__ __launch_bounds__(256) void detect_i64(const unsigned int* __restrict__ w,
                                                  int* __restrict__ flag) {
    __shared__ unsigned int red[256];
    unsigned int v = 0;
    for (int i = threadIdx.x; i < 4096; i += 256) v |= w[2 * i + 1];
    red[threadIdx.x] = v;
    __syncthreads();
    for (int s = 128; s > 0; s >>= 1) {
        if (threadIdx.x < s) red[threadIdx.x] |= red[threadIdx.x + s];
        __syncthreads();
    }
    if (threadIdx.x == 0) *flag = (red[0] == 0u) ? 1 : 0;
}

// ---------------------------------------------------------------------------
// Histogram of destination counts.
// ---------------------------------------------------------------------------
__global__ __launch_bounds__(256) void hist_k(const void* __restrict__ eidx,
                                              const int* __restrict__ flag,
                                              int* __restrict__ cnt) {
    int e = blockIdx.x * 256 + threadIdx.x;
    if (e >= NE) return;
    int dst;
    if (*flag) dst = (int)((const long long*)eidx)[NE + e];
    else       dst = ((const int*)eidx)[NE + e];
    atomicAdd(&cnt[dst], 1);
}

// ---------------------------------------------------------------------------
// Single-block exclusive scan over cnt[NN] -> offs[NN+1], also copies to cursor.
// ---------------------------------------------------------------------------
__global__ __launch_bounds__(1024) void scan_k(const int* __restrict__ cnt,
                                               int* __restrict__ offs,
                                               int* __restrict__ cursor) {
    __shared__ int wsum[16];
    __shared__ int carry_s;
    int tid = threadIdx.x;
    int lane = tid & 63;
    int wv = tid >> 6;
    if (tid == 0) carry_s = 0;
    __syncthreads();
    for (int base = 0; base < NN; base += 1024) {
        int i = base + tid;
        int v = (i < NN) ? cnt[i] : 0;
        int incl = v;
        #pragma unroll
        for (int d = 1; d < 64; d <<= 1) {
            int t = __shfl_up(incl, d);
            if (lane >= d) incl += t;
        }
        if (lane == 63) wsum[wv] = incl;
        __syncthreads();
        if (wv == 0) {
            int s = (lane < 16) ? wsum[lane] : 0;
            #pragma unroll
            for (int d = 1; d < 16; d <<= 1) {
                int t = __shfl_up(s, d);
                if (lane >= d) s += t;
            }
            if (lane < 16) wsum[lane] = s;  // inclusive over waves
        }
        __syncthreads();
        int wbase = (wv == 0) ? 0 : wsum[wv - 1];
        int carry = carry_s;
        int excl = carry + wbase + incl - v;
        if (i < NN) { offs[i] = excl; cursor[i] = excl; }
        __syncthreads();
        if (tid == 1023) carry_s = carry + wsum[15];
        __syncthreads();
    }
    if (threadIdx.x == 0) offs[NN] = carry_s;
}

// ---------------------------------------------------------------------------
// Scatter edges into CSR slots: csr[pos] = {src, weight_bits}.
// ---------------------------------------------------------------------------
__global__ __launch_bounds__(256) void fill_k(const void* __restrict__ eidx,
                                              const float* __restrict__ ew,
                                              const int* __restrict__ flag,
                                              int* __restrict__ cursor,
                                              int2* __restrict__ csr) {
    int e = blockIdx.x * 256 + threadIdx.x;
    if (e >= NE) return;
    int src, dst;
    if (*flag) {
        const long long* p = (const long long*)eidx;
        src = (int)p[e];
        dst = (int)p[NE + e];
    } else {
        const int* p = (const int*)eidx;
        src = p[e];
        dst = p[NE + e];
    }
    int pos = atomicAdd(&cursor[dst], 1);
    csr[pos] = make_int2(src, __float_as_int(ew[e]));
}

// ---------------------------------------------------------------------------
// One fused layer: per node (one wave, lane = channel).
// 512-thread blocks (8 waves) -> 4 blocks/CU = 32 waves/CU (100% occ).
// Edge loop unrolled x8 with clamped-index predication: 8 independent
// 256B row gathers in flight per wave to hide L2/L3 latency.
// ---------------------------------------------------------------------------
__global__ __launch_bounds__(512) void layer_k(const float* __restrict__ xin,
                                               const float* __restrict__ Wl,
                                               const float* __restrict__ bl,
                                               const int* __restrict__ offs,
                                               const int2* __restrict__ csr,
                                               float* __restrict__ xout) {
    __shared__ float Ws[128 * 64];
    int tid = threadIdx.x;
    // stage W[i] (128x64 f32 = 32 KB) into LDS, vectorized
    const float4* Wv = (const float4*)Wl;
    float4* Wsv = (float4*)Ws;
    #pragma unroll
    for (int i = 0; i < 4; ++i) Wsv[tid + 512 * i] = Wv[tid + 512 * i];
    __syncthreads();

    int wave = tid >> 6;
    int lane = tid & 63;
    int node = blockIdx.x * 8 + wave;

    // hoist own-row + bias loads to overlap with the gather loop
    float xl = xin[(size_t)node * DD + lane];
    float bias = bl[lane];

    int e0 = offs[node];
    int e1 = offs[node + 1];
    float acc = 0.f;
    for (int e = e0; e < e1; e += 8) {
        float wa[8], va[8];
        #pragma unroll
        for (int j = 0; j < 8; ++j) {
            int ej = e + j;
            int ec = (ej < e1) ? ej : (e1 - 1);   // clamp: always a valid slot
            int2 sw = csr[ec];
            wa[j] = (ej < e1) ? __int_as_float(sw.y) : 0.f;
            va[j] = xin[(size_t)sw.x * DD + lane];
        }
        #pragma unroll
        for (int j = 0; j < 8; ++j) acc += wa[j] * va[j];
    }

    // l2norm of aggr across the wave
    float sq = acc * acc;
    #pragma unroll
    for (int off = 32; off > 0; off >>= 1) sq += __shfl_xor(sq, off);
    float an = acc / fmaxf(sqrtf(sq), 1e-12f);

    float out = bias;
    #pragma unroll
    for (int k = 0; k < 64; ++k) {
        float ak = __shfl(an, k);   // compile-time lane -> broadcast
        float xk = __shfl(xl, k);
        out += ak * Ws[k * 64 + lane] + xk * Ws[(64 + k) * 64 + lane];
    }
    float osq = out * out;
    #pragma unroll
    for (int off = 32; off > 0; off >>= 1) osq += __shfl_xor(osq, off);
    xout[(size_t)node * DD + lane] = out / fmaxf(sqrtf(osq), 1e-12f);
}

// ---------------------------------------------------------------------------
extern "C" void kernel_launch(void* const* d_in, const int* in_sizes, int n_in,
                              void* d_out, int out_size, void* d_ws, size_t ws_size,
                              hipStream_t stream) {
    const float* x0  = (const float*)d_in[0];
    const void*  eidx = d_in[1];
    const float* ew  = (const float*)d_in[2];
    const float* W   = (const float*)d_in[3];
    const float* b   = (const float*)d_in[4];
    float* out = (float*)d_out;

    char* p = (char*)d_ws;
    auto alloc = [&](size_t bytes) {
        char* r = p;
        p += (bytes + 255) & ~(size_t)255;
        return r;
    };
    int*   flag   = (int*)alloc(4);
    int*   cnt    = (int*)alloc((size_t)NN * 4);
    int*   offs   = (int*)alloc((size_t)(NN + 1) * 4);
    int*   cursor = (int*)alloc((size_t)NN * 4);
    int2*  csr    = (int2*)alloc((size_t)NE * 8);
    float* bufA   = (float*)alloc((size_t)NN * DD * 4);

    hipMemsetAsync(cnt, 0, (size_t)NN * 4, stream);
    detect_i64<<<1, 256, 0, stream>>>((const unsigned int*)eidx, flag);
    hist_k<<<(NE + 255) / 256, 256, 0, stream>>>(eidx, flag, cnt);
    scan_k<<<1, 1024, 0, stream>>>(cnt, offs, cursor);
    fill_k<<<(NE + 255) / 256, 256, 0, stream>>>(eidx, ew, flag, cursor, csr);

    for (int i = 0; i < NL; ++i) {
        const float* xin = (i == 0) ? x0 : ((i % 2 == 1) ? bufA : out);
        float* xout = (i % 2 == 0) ? bufA : out;
        layer_k<<<NN / 8, 512, 0, stream>>>(xin, W + (size_t)i * 128 * 64,
                                            b + (size_t)i * 64, offs, csr, xout);
    }
}